// Round 23
// baseline (90.201 us; speedup 1.0000x reference)
//
#include <hip/hip_runtime.h>
#include <math.h>

#define NTOK 198
#define CCH  192

typedef float vf4 __attribute__((ext_vector_type(4)));

__device__ __forceinline__ float qgelu(float v) {
    return v / (1.0f + __expf(-1.702f * v));  // x * sigmoid(1.702 x)
}

__device__ __forceinline__ float dot8(const float4& a, const float4& wa,
                                      const float4& b, const float4& wb) {
    return a.x*wa.x + a.y*wa.y + a.z*wa.z + a.w*wa.w
         + b.x*wb.x + b.y*wb.y + b.z*wb.z + b.w*wb.w;
}

// ---- Phase A core: d-token idx via (i*nw + wv); w_down fragment in 24 regs ----
template <int NW>
__device__ __forceinline__ void phaseA(const float* __restrict__ x, int b,
                                       const float* __restrict__ w_down,
                                       const float* __restrict__ b_down,
                                       float* s_d, int lane, int wv)
{
    const int chunk = lane >> 3;
    const int dim   = lane & 7;
    float wreg[24];
    {
        const float* wp = w_down + dim * CCH + chunk * 24;
        #pragma unroll
        for (int j = 0; j < 24; ++j) wreg[j] = wp[j];
    }
    const float bd  = b_down[dim];
    const float* xb = x + (size_t)b * NTOK * CCH + chunk * 24;

    const int nIter = (NTOK - wv + NW - 1) / NW;   // wave-uniform
    #pragma unroll 1
    for (int i = 0; i < nIter; ++i) {
        const int idx = i * NW + wv;
        const bool valid = (idx < NTOK);
        const int n = valid ? idx : 0;             // safe addr for masked lanes
        const float* xr = xb + (size_t)n * CCH;
        float a0 = 0.f, a1 = 0.f;
        #pragma unroll
        for (int j = 0; j < 3; ++j) {
            const float4 xv = *(const float4*)(xr + j * 8);
            const float4 xw = *(const float4*)(xr + j * 8 + 4);
            a0 += xv.x*wreg[j*8]   + xv.y*wreg[j*8+1] + xv.z*wreg[j*8+2] + xv.w*wreg[j*8+3];
            a1 += xw.x*wreg[j*8+4] + xw.y*wreg[j*8+5] + xw.z*wreg[j*8+6] + xw.w*wreg[j*8+7];
        }
        float acc = a0 + a1;
        acc += __shfl_xor(acc, 8);
        acc += __shfl_xor(acc, 16);
        acc += __shfl_xor(acc, 32);
        if (valid && lane < 8) s_d[idx * 8 + dim] = qgelu(acc + bd);
    }
}

// ---- Phase B core: o-paired conv3x3 + qgelu (d-taps shared) ----
template <int NTHR>
__device__ __forceinline__ void phaseB(const float* s_d, float* s_d2,
                                       const float* s_cw, const float* s_cb, int tid)
{
    for (int j = tid; j < NTOK * 4; j += NTHR) {
        const int n = j >> 2, o2 = j & 3;
        const int oA = o2, oB = o2 + 4;
        if (n == 1) {
            s_d2[n * 8 + oA] = 0.0f;          // dist token zeroed; qgelu(0)=0
            s_d2[n * 8 + oB] = 0.0f;
        } else if (n == 0) {                  // cls: center tap only
            const float4 d0 = *(const float4*)&s_d[0];
            const float4 d1 = *(const float4*)&s_d[4];
            const float4 wa0 = *(const float4*)&s_cw[4 * 64 + oA * 8];
            const float4 wa1 = *(const float4*)&s_cw[4 * 64 + oA * 8 + 4];
            const float4 wb0 = *(const float4*)&s_cw[4 * 64 + oB * 8];
            const float4 wb1 = *(const float4*)&s_cw[4 * 64 + oB * 8 + 4];
            s_d2[n * 8 + oA] = qgelu(s_cb[oA] + dot8(d0, wa0, d1, wa1));
            s_d2[n * 8 + oB] = qgelu(s_cb[oB] + dot8(d0, wb0, d1, wb1));
        } else {
            const int pos = n - 2, h = pos / 14, w = pos % 14;
            float accA = s_cb[oA];
            float accB = s_cb[oB];
            #pragma unroll
            for (int dh = -1; dh <= 1; ++dh) {
                const int hh = h + dh;
                if (hh < 0 || hh > 13) continue;
                #pragma unroll
                for (int dw = -1; dw <= 1; ++dw) {
                    const int ww = w + dw;
                    if (ww < 0 || ww > 13) continue;
                    const int tok = 2 + hh * 14 + ww;
                    const int kk  = (dh + 1) * 3 + (dw + 1);
                    const float4 d0 = *(const float4*)&s_d[tok * 8];
                    const float4 d1 = *(const float4*)&s_d[tok * 8 + 4];
                    const float4 wa0 = *(const float4*)&s_cw[kk * 64 + oA * 8];
                    const float4 wa1 = *(const float4*)&s_cw[kk * 64 + oA * 8 + 4];
                    const float4 wb0 = *(const float4*)&s_cw[kk * 64 + oB * 8];
                    const float4 wb1 = *(const float4*)&s_cw[kk * 64 + oB * 8 + 4];
                    accA += dot8(d0, wa0, d1, wa1);
                    accB += dot8(d0, wb0, d1, wb1);
                }
            }
            s_d2[n * 8 + oA] = qgelu(accA);
            s_d2[n * 8 + oB] = qgelu(accB);
        }
    }
}

// ---- Phase C core: 512-thread up-proj, reg-resident w_up ----
__device__ __forceinline__ void phaseC(const float* s_d2,
                                       const float* __restrict__ w_up,
                                       const float* __restrict__ b_up,
                                       float* __restrict__ out, int b, int t512)
{
    const int c4 = t512 % 48;
    const int tl = t512 / 48;  // 0..10 (tl==10 idle)
    if (tl < 10) {
        float w_r[4][8];
        #pragma unroll
        for (int cc = 0; cc < 4; ++cc) {
            const float4 wa = *(const float4*)(w_up + (c4 * 4 + cc) * 8);
            const float4 wb = *(const float4*)(w_up + (c4 * 4 + cc) * 8 + 4);
            w_r[cc][0] = wa.x; w_r[cc][1] = wa.y; w_r[cc][2] = wa.z; w_r[cc][3] = wa.w;
            w_r[cc][4] = wb.x; w_r[cc][5] = wb.y; w_r[cc][6] = wb.z; w_r[cc][7] = wb.w;
        }
        const float4 bu = *(const float4*)(b_up + c4 * 4);
        float* outb = out + (size_t)b * NTOK * CCH;
        #pragma unroll 1
        for (int nr = tl; nr < NTOK; nr += 10) {
            const float4 da = *(const float4*)&s_d2[nr * 8];
            const float4 dv = *(const float4*)&s_d2[nr * 8 + 4];
            float accs[4] = {bu.x, bu.y, bu.z, bu.w};
            #pragma unroll
            for (int cc = 0; cc < 4; ++cc) {
                accs[cc] += da.x * w_r[cc][0] + da.y * w_r[cc][1]
                          + da.z * w_r[cc][2] + da.w * w_r[cc][3]
                          + dv.x * w_r[cc][4] + dv.y * w_r[cc][5]
                          + dv.z * w_r[cc][6] + dv.w * w_r[cc][7];
            }
            const vf4 r = {accs[0], accs[1], accs[2], accs[3]};
            __builtin_nontemporal_store(r, (vf4*)(outb + (size_t)nr * CCH + c4 * 4));
        }
    }
}

// R23: intra-block wave-specialized pipeline. 1024-thr block handles TWO batch
// elements; in the overlap region waves 0-7 run C(e0) (write stream) while waves
// 8-15 run A(e1) (read stream) -- disjoint LDS buffers (s_d2 vs s_d), no extra
// barriers, no halo. Grid 512 = 2 blocks/CU = full residency. Phase internals
// are R20-verbatim. (1024,2): cap 128 (no spill risk); body ~40 -> 8 waves/SIMD.
__global__ __launch_bounds__(1024, 2) void convpass_fused(
    const float* __restrict__ x,       // [B,198,192]
    const float* __restrict__ w_down,  // [8,192]
    const float* __restrict__ b_down,  // [8]
    const float* __restrict__ conv_w,  // [8,8,3,3]
    const float* __restrict__ conv_b,  // [8]
    const float* __restrict__ w_up,    // [192,8]
    const float* __restrict__ b_up,    // [192]
    float* __restrict__ out)           // [B,198,192]
{
    const int e0  = blockIdx.x * 2;
    const int e1  = e0 + 1;
    const int tid = threadIdx.x;

    __shared__ float s_d[NTOK * 8];   // 6336 B
    __shared__ float s_d2[NTOK * 8];  // 6336 B
    __shared__ float s_cw[576];       // 2304 B
    __shared__ float s_cb[8];

    for (int t = tid; t < 576; t += 1024) {
        const int kk = t >> 6, rem = t & 63, o = rem >> 3, i = rem & 7;
        s_cw[t] = conv_w[(o * 8 + i) * 9 + kk];   // [kk][o][i] <- [o][i][kk]
    }
    if (tid < 8) s_cb[tid] = conv_b[tid];

    const int lane = tid & 63;
    const int wv16 = tid >> 6;        // 0..15

    // ---- A(e0): all 16 waves ----
    phaseA<16>(x, e0, w_down, b_down, s_d, lane, wv16);
    __syncthreads();
    // ---- B(e0) ----
    phaseB<1024>(s_d, s_d2, s_cw, s_cb, tid);
    __syncthreads();
    // ---- overlap: waves 0-7 C(e0)  ||  waves 8-15 A(e1) ----
    if (tid < 512) {
        phaseC(s_d2, w_up, b_up, out, e0, tid);
    } else {
        phaseA<8>(x, e1, w_down, b_down, s_d, lane, wv16 - 8);
    }
    __syncthreads();
    // ---- B(e1) ----
    phaseB<1024>(s_d, s_d2, s_cw, s_cb, tid);
    __syncthreads();
    // ---- C(e1): waves 0-7 (same width as R20's C) ----
    if (tid < 512) {
        phaseC(s_d2, w_up, b_up, out, e1, tid);
    }
}

extern "C" void kernel_launch(void* const* d_in, const int* in_sizes, int n_in,
                              void* d_out, int out_size, void* d_ws, size_t ws_size,
                              hipStream_t stream) {
    const float* x      = (const float*)d_in[0];
    const float* w_down = (const float*)d_in[1];
    const float* b_down = (const float*)d_in[2];
    const float* conv_w = (const float*)d_in[3];
    const float* conv_b = (const float*)d_in[4];
    const float* w_up   = (const float*)d_in[5];
    const float* b_up   = (const float*)d_in[6];
    float* out = (float*)d_out;

    const int B = in_sizes[0] / (NTOK * CCH);   // 1024
    convpass_fused<<<dim3(B / 2), dim3(1024), 0, stream>>>(
        x, w_down, b_down, conv_w, conv_b, w_up, b_up, out);
}

// Round 24
// 75.660 us; speedup vs baseline: 1.1922x; 1.1922x over previous
//
#include <hip/hip_runtime.h>
#include <math.h>

#define NTOK 198
#define CCH  192

typedef float vf4 __attribute__((ext_vector_type(4)));

__device__ __forceinline__ float qgelu(float v) {
    return v / (1.0f + __expf(-1.702f * v));  // x * sigmoid(1.702 x)
}

__device__ __forceinline__ float dot8(const float4& a, const float4& wa,
                                      const float4& b, const float4& wb) {
    return a.x*wa.x + a.y*wa.y + a.z*wa.z + a.w*wa.w
         + b.x*wb.x + b.y*wb.y + b.z*wb.z + b.w*wb.w;
}

// Fully fused: down-proj + qgelu -> conv3x3 + qgelu -> up-proj.  [R20 FINAL]
// ONE 512-thread block per batch element, grid 1024 = exact one fill, 4 blocks/CU.
// (512,4): 64-VGPR cap; body ~32 regs -> 8 waves/SIMD, 63% occupancy.
// Phase A: lane=(chunk,dim), w_down fragment in 24 REGISTERS, no LDS, 3-shfl
//   all-reduce. Phase B: o-paired conv (d-taps shared). Phase C: reg-resident w_up.
// Falsified alternatives (counters in journal): kernel split (R2/R19), manual
// dbuf/2-token pipelines (R9/R17), sub-64 squeeze of fat bodies (R7/R10/R13/R14,
// spill = +300..600MB scratch), two-fill stagger (R21), wave-specialized
// producer/consumer (R23). Best reproduced: 75.7-75.9us; FETCH 76MB, WRITE 152MB
// exact, 0 conflicts, no spill, no saturated pipe.
__global__ __launch_bounds__(512, 4) void convpass_fused(
    const float* __restrict__ x,       // [B,198,192]
    const float* __restrict__ w_down,  // [8,192]
    const float* __restrict__ b_down,  // [8]
    const float* __restrict__ conv_w,  // [8,8,3,3]
    const float* __restrict__ conv_b,  // [8]
    const float* __restrict__ w_up,    // [192,8]
    const float* __restrict__ b_up,    // [192]
    float* __restrict__ out)           // [B,198,192]
{
    const int b   = blockIdx.x;
    const int tid = threadIdx.x;

    __shared__ float s_d[NTOK * 8];   // 6336 B  down-proj out (stride 8: b128 rows)
    __shared__ float s_d2[NTOK * 8];  // 6336 B  conv out
    __shared__ float s_cw[576];       // 2304 B  conv weights [kk][o][i]
    __shared__ float s_cb[8];

    // ---- stage conv weights (visibility covered by the barrier after Phase A) ----
    for (int t = tid; t < 576; t += 512) {
        const int kk = t >> 6, rem = t & 63, o = rem >> 3, i = rem & 7;
        s_cw[t] = conv_w[(o * 8 + i) * 9 + kk];   // [kk][o][i] <- [o][i][kk]
    }
    if (tid < 8) s_cb[tid] = conv_b[tid];

    // ========== Phase A: d = qgelu(x @ w_down^T + b_down) -> s_d ==========
    {
        const int lane  = tid & 63;
        const int wv    = tid >> 6;       // wave 0..7
        const int chunk = lane >> 3;      // 24-float c-chunk 0..7
        const int dim   = lane & 7;       // output dim 0..7

        float wreg[24];
        {
            const float* wp = w_down + dim * CCH + chunk * 24;
            #pragma unroll
            for (int j = 0; j < 24; ++j) wreg[j] = wp[j];
        }
        const float bd  = b_down[dim];
        const float* xb = x + (size_t)b * NTOK * CCH + chunk * 24;

        const int nIter = (NTOK - wv + 7) >> 3;   // wave-uniform: 25 (wv<6) or 24
        #pragma unroll 1
        for (int i = 0; i < nIter; ++i) {
            const int idx = i * 8 + wv;               // 0..197
            const bool valid = (idx < NTOK);
            const int n = valid ? idx : 0;            // safe addr for masked lanes
            const float* xr = xb + (size_t)n * CCH;
            // 6 independent b128 loads (8-lane broadcast groups), 2 FMA chains
            float a0 = 0.f, a1 = 0.f;
            #pragma unroll
            for (int j = 0; j < 3; ++j) {
                const float4 xv = *(const float4*)(xr + j * 8);
                const float4 xw = *(const float4*)(xr + j * 8 + 4);
                a0 += xv.x*wreg[j*8]   + xv.y*wreg[j*8+1] + xv.z*wreg[j*8+2] + xv.w*wreg[j*8+3];
                a1 += xw.x*wreg[j*8+4] + xw.y*wreg[j*8+5] + xw.z*wreg[j*8+6] + xw.w*wreg[j*8+7];
            }
            float acc = a0 + a1;
            // all-reduce over the 8 chunks (lane bits 3,4,5)
            acc += __shfl_xor(acc, 8);
            acc += __shfl_xor(acc, 16);
            acc += __shfl_xor(acc, 32);
            if (valid && lane < 8) s_d[idx * 8 + dim] = qgelu(acc + bd);
        }
    }
    __syncthreads();

    // ========== Phase B: conv3x3 + qgelu -> s_d2 (o-paired: d-taps shared) ==========
    for (int j = tid; j < NTOK * 4; j += 512) {
        const int n = j >> 2, o2 = j & 3;     // o-pair: o2 and o2+4
        const int oA = o2, oB = o2 + 4;
        if (n == 1) {
            s_d2[n * 8 + oA] = 0.0f;          // dist token zeroed; qgelu(0)=0
            s_d2[n * 8 + oB] = 0.0f;
        } else if (n == 0) {                  // cls: center tap only
            const float4 d0 = *(const float4*)&s_d[0];
            const float4 d1 = *(const float4*)&s_d[4];
            const float4 wa0 = *(const float4*)&s_cw[4 * 64 + oA * 8];
            const float4 wa1 = *(const float4*)&s_cw[4 * 64 + oA * 8 + 4];
            const float4 wb0 = *(const float4*)&s_cw[4 * 64 + oB * 8];
            const float4 wb1 = *(const float4*)&s_cw[4 * 64 + oB * 8 + 4];
            s_d2[n * 8 + oA] = qgelu(s_cb[oA] + dot8(d0, wa0, d1, wa1));
            s_d2[n * 8 + oB] = qgelu(s_cb[oB] + dot8(d0, wb0, d1, wb1));
        } else {
            const int pos = n - 2, h = pos / 14, w = pos % 14;
            float accA = s_cb[oA];
            float accB = s_cb[oB];
            #pragma unroll
            for (int dh = -1; dh <= 1; ++dh) {
                const int hh = h + dh;
                if (hh < 0 || hh > 13) continue;
                #pragma unroll
                for (int dw = -1; dw <= 1; ++dw) {
                    const int ww = w + dw;
                    if (ww < 0 || ww > 13) continue;
                    const int tok = 2 + hh * 14 + ww;
                    const int kk  = (dh + 1) * 3 + (dw + 1);
                    const float4 d0 = *(const float4*)&s_d[tok * 8];      // shared taps
                    const float4 d1 = *(const float4*)&s_d[tok * 8 + 4];
                    const float4 wa0 = *(const float4*)&s_cw[kk * 64 + oA * 8];
                    const float4 wa1 = *(const float4*)&s_cw[kk * 64 + oA * 8 + 4];
                    const float4 wb0 = *(const float4*)&s_cw[kk * 64 + oB * 8];
                    const float4 wb1 = *(const float4*)&s_cw[kk * 64 + oB * 8 + 4];
                    accA += dot8(d0, wa0, d1, wa1);
                    accB += dot8(d0, wb0, d1, wb1);
                }
            }
            s_d2[n * 8 + oA] = qgelu(accA);
            s_d2[n * 8 + oB] = qgelu(accB);
        }
    }
    __syncthreads();

    // ========== Phase C: out = d2 @ w_up^T + b_up ==========
    const int c4 = tid % 48;
    const int tl = tid / 48;  // 0..10 (tl==10: 32 threads idle)
    if (tl < 10) {
        float w_r[4][8];
        #pragma unroll
        for (int cc = 0; cc < 4; ++cc) {
            const float4 wa = *(const float4*)(w_up + (c4 * 4 + cc) * 8);
            const float4 wb = *(const float4*)(w_up + (c4 * 4 + cc) * 8 + 4);
            w_r[cc][0] = wa.x; w_r[cc][1] = wa.y; w_r[cc][2] = wa.z; w_r[cc][3] = wa.w;
            w_r[cc][4] = wb.x; w_r[cc][5] = wb.y; w_r[cc][6] = wb.z; w_r[cc][7] = wb.w;
        }
        const float4 bu = *(const float4*)(b_up + c4 * 4);
        float* outb = out + (size_t)b * NTOK * CCH;
        #pragma unroll 1
        for (int nr = tl; nr < NTOK; nr += 10) {
            const float4 da = *(const float4*)&s_d2[nr * 8];      // broadcast
            const float4 dv = *(const float4*)&s_d2[nr * 8 + 4];
            float accs[4] = {bu.x, bu.y, bu.z, bu.w};
            #pragma unroll
            for (int cc = 0; cc < 4; ++cc) {
                accs[cc] += da.x * w_r[cc][0] + da.y * w_r[cc][1]
                          + da.z * w_r[cc][2] + da.w * w_r[cc][3]
                          + dv.x * w_r[cc][4] + dv.y * w_r[cc][5]
                          + dv.z * w_r[cc][6] + dv.w * w_r[cc][7];
            }
            const vf4 r = {accs[0], accs[1], accs[2], accs[3]};
            __builtin_nontemporal_store(r, (vf4*)(outb + (size_t)nr * CCH + c4 * 4));
        }
    }
}

extern "C" void kernel_launch(void* const* d_in, const int* in_sizes, int n_in,
                              void* d_out, int out_size, void* d_ws, size_t ws_size,
                              hipStream_t stream) {
    const float* x      = (const float*)d_in[0];
    const float* w_down = (const float*)d_in[1];
    const float* b_down = (const float*)d_in[2];
    const float* conv_w = (const float*)d_in[3];
    const float* conv_b = (const float*)d_in[4];
    const float* w_up   = (const float*)d_in[5];
    const float* b_up   = (const float*)d_in[6];
    float* out = (float*)d_out;

    const int B = in_sizes[0] / (NTOK * CCH);   // 1024
    convpass_fused<<<dim3(B), dim3(512), 0, stream>>>(
        x, w_down, b_down, conv_w, conv_b, w_up, b_up, out);
}